// Round 2
// baseline (282.912 us; speedup 1.0000x reference)
//
#include <hip/hip_runtime.h>
#include <stdint.h>

typedef __bf16 bf16x8 __attribute__((ext_vector_type(8)));
typedef float f32x4 __attribute__((ext_vector_type(4)));

constexpr int NB = 8;     // batches
constexpr int N  = 2048;  // nodes
constexpr int F  = 128;   // features (in == out)

__device__ __forceinline__ unsigned short bf16r(float f) {
    unsigned u = __float_as_uint(f);
    return (unsigned short)((u + 0x7FFFu + ((u >> 16) & 1u)) >> 16);
}
__device__ __forceinline__ float bf2f(unsigned short s) {
    return __uint_as_float(((unsigned)s) << 16);
}

// ---------------------------------------------------------------------------
// Wb element layout (MFMA-B-operand native):
//   E(b, n, o) = b*N*F + (n>>3)*1024 + o*8 + (n&7)
// A lane needing B[k = kb+quad*8 .. +8][o] reads 8 contiguous bf16 at
//   base + ((kb>>3)+quad)*1024 + o*8  -> 16B load, 256B contiguous per quad.
// ---------------------------------------------------------------------------

// K1: Wb[b][n][o] (bf16, blocked layout) = sum_f h[b][n][f] * W[o][f]
// Block: 64 n-rows x 128 o-cols, 4 waves (2x2 wm/wn), wave tile 32x64.
__global__ __launch_bounds__(256) void k1_wh(const float* __restrict__ h,
                                             const float* __restrict__ W,
                                             unsigned short* __restrict__ Wb) {
    const int tid  = threadIdx.x;
    const int lane = tid & 63, wid = tid >> 6;
    const int quad = lane >> 4, l15 = lane & 15;
    const int wm = wid >> 1, wn = wid & 1;
    const int m0 = blockIdx.x * 64;
    const int batch = m0 >> 11;
    const int nbase = m0 & 2047;

    f32x4 acc[2][4] = {};

#pragma unroll
    for (int kk = 0; kk < 4; ++kk) {
        const int k = kk * 32 + quad * 8;
        bf16x8 afr[2], bfr[4];
#pragma unroll
        for (int rt = 0; rt < 2; ++rt) {
            const float* src = h + (size_t)(m0 + wm * 32 + rt * 16 + l15) * F + k;
            float4 x0 = *(const float4*)src;
            float4 x1 = *(const float4*)(src + 4);
            afr[rt][0] = (__bf16)x0.x; afr[rt][1] = (__bf16)x0.y;
            afr[rt][2] = (__bf16)x0.z; afr[rt][3] = (__bf16)x0.w;
            afr[rt][4] = (__bf16)x1.x; afr[rt][5] = (__bf16)x1.y;
            afr[rt][6] = (__bf16)x1.z; afr[rt][7] = (__bf16)x1.w;
        }
#pragma unroll
        for (int ct = 0; ct < 4; ++ct) {
            const int o = wn * 64 + ct * 16 + l15;
            const float* src = W + (size_t)o * F + k;
            float4 x0 = *(const float4*)src;
            float4 x1 = *(const float4*)(src + 4);
            bfr[ct][0] = (__bf16)x0.x; bfr[ct][1] = (__bf16)x0.y;
            bfr[ct][2] = (__bf16)x0.z; bfr[ct][3] = (__bf16)x0.w;
            bfr[ct][4] = (__bf16)x1.x; bfr[ct][5] = (__bf16)x1.y;
            bfr[ct][6] = (__bf16)x1.z; bfr[ct][7] = (__bf16)x1.w;
        }
#pragma unroll
        for (int rt = 0; rt < 2; ++rt)
#pragma unroll
            for (int ct = 0; ct < 4; ++ct)
                acc[rt][ct] = __builtin_amdgcn_mfma_f32_16x16x32_bf16(
                    afr[rt], bfr[ct], acc[rt][ct], 0, 0, 0);
    }

    // C/D: col = l15, row = quad*4 + reg. 4 consecutive n per lane live in the
    // same 8-chunk at sub-offset (quad&1)*4 -> one 8B store.
#pragma unroll
    for (int rt = 0; rt < 2; ++rt)
#pragma unroll
        for (int ct = 0; ct < 4; ++ct) {
            const int o  = wn * 64 + ct * 16 + l15;
            const int n0 = nbase + wm * 32 + rt * 16 + quad * 4;
            size_t off = (size_t)batch * N * F + (size_t)(n0 >> 3) * 1024 + o * 8 + (n0 & 7);
            ushort4 v;
            v.x = bf16r(acc[rt][ct][0]); v.y = bf16r(acc[rt][ct][1]);
            v.z = bf16r(acc[rt][ct][2]); v.w = bf16r(acc[rt][ct][3]);
            *(ushort4*)&Wb[off] = v;
        }
}

// K2: per node j: e = sum_o Wb[j][o]*a2[o]; p = exp(e);
//     p16[b][j] = bf16(p);  Wb2[j][o] = bf16(p * Wb[j][o])
__global__ __launch_bounds__(256) void k2_scale(const unsigned short* __restrict__ Wb,
                                               const float* __restrict__ a,
                                               unsigned short* __restrict__ Wb2,
                                               unsigned short* __restrict__ p16) {
    const int gid = blockIdx.x * 256 + threadIdx.x;   // 0..NB*N-1
    const int b = gid >> 11, j = gid & 2047;
    const size_t base = (size_t)b * N * F + (size_t)(j >> 3) * 1024 + (j & 7);
    const unsigned short* src = Wb + base;
    float e = 0.f;
#pragma unroll 8
    for (int o = 0; o < F; ++o)
        e += bf2f(src[o * 8]) * a[F + o];
    unsigned short pb = bf16r(expf(e));
    p16[gid] = pb;
    const float pf = bf2f(pb);     // use the rounded p for num/denom consistency
    unsigned short* dst = Wb2 + base;
#pragma unroll 8
    for (int o = 0; o < F; ++o)
        dst[o * 8] = bf16r(pf * bf2f(src[o * 8]));
}

// K3: out[b][i][o] = (sum_j adj[b][i][j] * Wb2[j][o]) / (sum_j adj * p[j])
// Barrier-free, LDS-free register pipeline. Block tile 32(i) x 128(o),
// 4 waves (2x2), wave tile 16x64. adj loads non-temporal (read-once stream,
// keep Wb2 hot in L2). Denominator via extra MFMA against p-broadcast B frag.
__global__ __launch_bounds__(256, 2) void k3_attn(const float* __restrict__ adj,
                                                  const unsigned short* __restrict__ Wb2,
                                                  const unsigned short* __restrict__ p16,
                                                  float* __restrict__ out) {
    const int tid  = threadIdx.x;
    const int lane = tid & 63, wid = tid >> 6;
    const int quad = lane >> 4, l15 = lane & 15;
    const int wm = wid >> 1, wn = wid & 1;
    const int b  = blockIdx.x >> 6;
    const int i0 = (blockIdx.x & 63) * 32;

    // A: per-lane row pointer; lane reads adj[i0+wm*16+l15][kb + quad*8 .. +8]
    const float* ar = adj + (size_t)b * N * N + (size_t)(i0 + wm * 16 + l15) * N + quad * 8;
    // B: bytes = b*N*F*2 + ((kb>>3)+quad)*2048 + o*16, o = wn*64 + ct*16 + l15
    const char* bB = (const char*)(Wb2 + (size_t)b * N * F) + quad * 2048 + wn * 1024 + l15 * 16;
    // p (denominator B frag): 16B at quad-uniform address
    const unsigned short* pq = p16 + b * N + quad * 8;

    f32x4 acc[4] = {};
    f32x4 dacc = {};

#pragma unroll 4
    for (int kb = 0; kb < N; kb += 32) {
        f32x4 x0 = __builtin_nontemporal_load((const f32x4*)(ar + kb));
        f32x4 x1 = __builtin_nontemporal_load((const f32x4*)(ar + kb + 4));
        bf16x8 bp = *(const bf16x8*)(pq + kb);
        bf16x8 b0 = *(const bf16x8*)(bB + (size_t)kb * 256);
        bf16x8 b1 = *(const bf16x8*)(bB + (size_t)kb * 256 + 256);
        bf16x8 b2 = *(const bf16x8*)(bB + (size_t)kb * 256 + 512);
        bf16x8 b3 = *(const bf16x8*)(bB + (size_t)kb * 256 + 768);

        bf16x8 af;   // adj is {0,1}: cvt is exact, p already folded into B
        af[0] = (__bf16)x0[0]; af[1] = (__bf16)x0[1];
        af[2] = (__bf16)x0[2]; af[3] = (__bf16)x0[3];
        af[4] = (__bf16)x1[0]; af[5] = (__bf16)x1[1];
        af[6] = (__bf16)x1[2]; af[7] = (__bf16)x1[3];

        acc[0] = __builtin_amdgcn_mfma_f32_16x16x32_bf16(af, b0, acc[0], 0, 0, 0);
        acc[1] = __builtin_amdgcn_mfma_f32_16x16x32_bf16(af, b1, acc[1], 0, 0, 0);
        acc[2] = __builtin_amdgcn_mfma_f32_16x16x32_bf16(af, b2, acc[2], 0, 0, 0);
        acc[3] = __builtin_amdgcn_mfma_f32_16x16x32_bf16(af, b3, acc[3], 0, 0, 0);
        dacc   = __builtin_amdgcn_mfma_f32_16x16x32_bf16(af, bp, dacc, 0, 0, 0);
    }

    // dacc reg g = denom for row quad*4+g (all cols identical) — same row
    // mapping as acc, so the divide is lane-local.
    float inv[4];
#pragma unroll
    for (int g = 0; g < 4; ++g) inv[g] = 1.0f / dacc[g];

    float* ob = out + (size_t)b * N * F;
#pragma unroll
    for (int ct = 0; ct < 4; ++ct) {
        const int o = wn * 64 + ct * 16 + l15;
#pragma unroll
        for (int g = 0; g < 4; ++g) {
            const int i = i0 + wm * 16 + quad * 4 + g;
            __builtin_nontemporal_store(acc[ct][g] * inv[g], &ob[(size_t)i * F + o]);
        }
    }
}

// ---------------------------------------------------------------------------
extern "C" void kernel_launch(void* const* d_in, const int* in_sizes, int n_in,
                              void* d_out, int out_size, void* d_ws, size_t ws_size,
                              hipStream_t stream) {
    const float* h   = (const float*)d_in[0];
    const float* adj = (const float*)d_in[1];
    const float* W   = (const float*)d_in[2];
    const float* a   = (const float*)d_in[3];
    float* out = (float*)d_out;

    unsigned short* Wb  = (unsigned short*)d_ws;                          // 4 MB
    unsigned short* Wb2 = (unsigned short*)((char*)d_ws + (4u << 20));    // 4 MB
    unsigned short* p16 = (unsigned short*)((char*)d_ws + (8u << 20));    // 32 KB

    k1_wh<<<NB * N / 64, 256, 0, stream>>>(h, W, Wb);
    k2_scale<<<NB * N / 256, 256, 0, stream>>>(Wb, a, Wb2, p16);
    k3_attn<<<NB * (N / 32), 256, 0, stream>>>(adj, Wb2, p16, out);
}

// Round 3
// 252.408 us; speedup vs baseline: 1.1209x; 1.1209x over previous
//
#include <hip/hip_runtime.h>
#include <stdint.h>

typedef __bf16 bf16x8 __attribute__((ext_vector_type(8)));
typedef float f32x4 __attribute__((ext_vector_type(4)));
typedef unsigned short u16x8 __attribute__((ext_vector_type(8)));

constexpr int NB = 8;     // batches
constexpr int N  = 2048;  // nodes
constexpr int F  = 128;   // features (in == out)

__device__ __forceinline__ unsigned short bf16r(float f) {
    unsigned u = __float_as_uint(f);
    return (unsigned short)((u + 0x7FFFu + ((u >> 16) & 1u)) >> 16);
}
__device__ __forceinline__ float bf2f(unsigned short s) {
    return __uint_as_float(((unsigned)s) << 16);
}

// ---------------------------------------------------------------------------
// Wb element layout (MFMA-B-operand native):
//   E(b, n, o) = b*N*F + (n>>3)*1024 + o*8 + (n&7)
// A lane needing B[k = kb+quad*8 .. +8][o] reads 8 contiguous bf16 at
//   base + ((kb>>3)+quad)*1024 + o*8  -> one 16B load.
// ---------------------------------------------------------------------------

// K1: Wb[b][n][o] (bf16, blocked layout) = sum_f h[b][n][f] * W[o][f]
__global__ __launch_bounds__(256) void k1_wh(const float* __restrict__ h,
                                             const float* __restrict__ W,
                                             unsigned short* __restrict__ Wb) {
    const int tid  = threadIdx.x;
    const int lane = tid & 63, wid = tid >> 6;
    const int quad = lane >> 4, l15 = lane & 15;
    const int wm = wid >> 1, wn = wid & 1;
    const int m0 = blockIdx.x * 64;
    const int batch = m0 >> 11;
    const int nbase = m0 & 2047;

    f32x4 acc[2][4] = {};

#pragma unroll
    for (int kk = 0; kk < 4; ++kk) {
        const int k = kk * 32 + quad * 8;
        bf16x8 afr[2], bfr[4];
#pragma unroll
        for (int rt = 0; rt < 2; ++rt) {
            const float* src = h + (size_t)(m0 + wm * 32 + rt * 16 + l15) * F + k;
            float4 x0 = *(const float4*)src;
            float4 x1 = *(const float4*)(src + 4);
            afr[rt][0] = (__bf16)x0.x; afr[rt][1] = (__bf16)x0.y;
            afr[rt][2] = (__bf16)x0.z; afr[rt][3] = (__bf16)x0.w;
            afr[rt][4] = (__bf16)x1.x; afr[rt][5] = (__bf16)x1.y;
            afr[rt][6] = (__bf16)x1.z; afr[rt][7] = (__bf16)x1.w;
        }
#pragma unroll
        for (int ct = 0; ct < 4; ++ct) {
            const int o = wn * 64 + ct * 16 + l15;
            const float* src = W + (size_t)o * F + k;
            float4 x0 = *(const float4*)src;
            float4 x1 = *(const float4*)(src + 4);
            bfr[ct][0] = (__bf16)x0.x; bfr[ct][1] = (__bf16)x0.y;
            bfr[ct][2] = (__bf16)x0.z; bfr[ct][3] = (__bf16)x0.w;
            bfr[ct][4] = (__bf16)x1.x; bfr[ct][5] = (__bf16)x1.y;
            bfr[ct][6] = (__bf16)x1.z; bfr[ct][7] = (__bf16)x1.w;
        }
#pragma unroll
        for (int rt = 0; rt < 2; ++rt)
#pragma unroll
            for (int ct = 0; ct < 4; ++ct)
                acc[rt][ct] = __builtin_amdgcn_mfma_f32_16x16x32_bf16(
                    afr[rt], bfr[ct], acc[rt][ct], 0, 0, 0);
    }

#pragma unroll
    for (int rt = 0; rt < 2; ++rt)
#pragma unroll
        for (int ct = 0; ct < 4; ++ct) {
            const int o  = wn * 64 + ct * 16 + l15;
            const int n0 = nbase + wm * 32 + rt * 16 + quad * 4;
            size_t off = (size_t)batch * N * F + (size_t)(n0 >> 3) * 1024 + o * 8 + (n0 & 7);
            ushort4 v;
            v.x = bf16r(acc[rt][ct][0]); v.y = bf16r(acc[rt][ct][1]);
            v.z = bf16r(acc[rt][ct][2]); v.w = bf16r(acc[rt][ct][3]);
            *(ushort4*)&Wb[off] = v;
        }
}

// K2: one wave per 8-node group (the 2KB-contiguous blocks of Wb).
//   e[j] = sum_o Wb[j][o]*a2[o]; p = exp(e);  p16 = bf16(p);
//   Wb2[j][o] = bf16(p * Wb[j][o])
// Lane l holds o = {2l, 2l+1} for all 8 nodes of its group (32B load).
__global__ __launch_bounds__(256) void k2_scale(const unsigned short* __restrict__ Wb,
                                                const float* __restrict__ a,
                                                unsigned short* __restrict__ Wb2,
                                                unsigned short* __restrict__ p16) {
    const int tid  = threadIdx.x;
    const int lane = tid & 63, wid = tid >> 6;
    const int g = blockIdx.x * 4 + wid;      // group id, 0 .. NB*N/8-1
    const int b = g >> 8, grp = g & 255;

    const size_t base = (size_t)b * N * F + (size_t)grp * 1024 + lane * 16;
    bf16x8 v0 = *(const bf16x8*)(Wb + base);       // o = 2*lane,  nn = 0..7
    bf16x8 v1 = *(const bf16x8*)(Wb + base + 8);   // o = 2*lane+1

    const float a0 = a[F + 2 * lane], a1 = a[F + 2 * lane + 1];
    float part[8];
#pragma unroll
    for (int nn = 0; nn < 8; ++nn)
        part[nn] = (float)v0[nn] * a0 + (float)v1[nn] * a1;

#pragma unroll
    for (int m = 1; m < 64; m <<= 1)
#pragma unroll
        for (int nn = 0; nn < 8; ++nn)
            part[nn] += __shfl_xor(part[nn], m);

    u16x8 pv;
    float pf[8];
#pragma unroll
    for (int nn = 0; nn < 8; ++nn) {
        unsigned short pb = bf16r(expf(part[nn]));
        pv[nn] = pb;
        pf[nn] = bf2f(pb);     // rounded p for num/denom consistency
    }
    if (lane == 0)
        *(u16x8*)&p16[b * N + grp * 8] = pv;

    bf16x8 w0, w1;
#pragma unroll
    for (int nn = 0; nn < 8; ++nn) {
        w0[nn] = (__bf16)bf2f(bf16r(pf[nn] * (float)v0[nn]));
        w1[nn] = (__bf16)bf2f(bf16r(pf[nn] * (float)v1[nn]));
    }
    *(bf16x8*)(Wb2 + base)     = w0;
    *(bf16x8*)(Wb2 + base + 8) = w1;
}

// K3: out[b][i][o] = (sum_j adj[b][i][j] * Wb2[j][o]) / (sum_j adj * p[j])
// Barrier/LDS-free. Block 32(i) x 128(o), 4 waves (2x2), wave tile 16x64.
// Explicit software pipeline: A (adj, HBM/L3) staged 8 chunks deep in named
// registers; B+p (L2-resident) staged 2 deep. Chunk = 32 k.
__global__ __launch_bounds__(256, 2) void k3_attn(const float* __restrict__ adj,
                                                  const unsigned short* __restrict__ Wb2,
                                                  const unsigned short* __restrict__ p16,
                                                  float* __restrict__ out) {
    const int tid  = threadIdx.x;
    const int lane = tid & 63, wid = tid >> 6;
    const int quad = lane >> 4, l15 = lane & 15;
    const int wm = wid >> 1, wn = wid & 1;
    const int b  = blockIdx.x >> 6;
    const int i0 = (blockIdx.x & 63) * 32;

    const float* ar = adj + (size_t)b * N * N + (size_t)(i0 + wm * 16 + l15) * N + quad * 8;
    const char*  bB = (const char*)(Wb2 + (size_t)b * N * F) + quad * 2048 + wn * 1024 + l15 * 16;
    const unsigned short* pq = p16 + b * N + quad * 8;

    f32x4 acc[4] = {};
    f32x4 dacc = {};

    f32x4  xa[8][2];   // A staging: 8 chunks in flight (64 VGPRs)
    bf16x8 xb[2][5];   // B+p staging: 2 chunks (40 VGPRs)

    auto chunkA = [&](int c, int s) {
        xa[s][0] = __builtin_nontemporal_load((const f32x4*)(ar + c * 32));
        xa[s][1] = __builtin_nontemporal_load((const f32x4*)(ar + c * 32 + 4));
    };
    auto chunkB = [&](int c, int s) {
        const char* p = bB + (size_t)c * 8192;
        xb[s][0] = *(const bf16x8*)(p);
        xb[s][1] = *(const bf16x8*)(p + 256);
        xb[s][2] = *(const bf16x8*)(p + 512);
        xb[s][3] = *(const bf16x8*)(p + 768);
        xb[s][4] = *(const bf16x8*)(pq + c * 32);
    };
    auto compute = [&](int s, int bs) {
        f32x4 x0 = xa[s][0], x1 = xa[s][1];
        bf16x8 af;   // adj in {0,1}: cvt exact; p folded into B
        af[0] = (__bf16)x0[0]; af[1] = (__bf16)x0[1];
        af[2] = (__bf16)x0[2]; af[3] = (__bf16)x0[3];
        af[4] = (__bf16)x1[0]; af[5] = (__bf16)x1[1];
        af[6] = (__bf16)x1[2]; af[7] = (__bf16)x1[3];
        acc[0] = __builtin_amdgcn_mfma_f32_16x16x32_bf16(af, xb[bs][0], acc[0], 0, 0, 0);
        acc[1] = __builtin_amdgcn_mfma_f32_16x16x32_bf16(af, xb[bs][1], acc[1], 0, 0, 0);
        acc[2] = __builtin_amdgcn_mfma_f32_16x16x32_bf16(af, xb[bs][2], acc[2], 0, 0, 0);
        acc[3] = __builtin_amdgcn_mfma_f32_16x16x32_bf16(af, xb[bs][3], acc[3], 0, 0, 0);
        dacc   = __builtin_amdgcn_mfma_f32_16x16x32_bf16(af, xb[bs][4], dacc,   0, 0, 0);
    };

    // prologue
#pragma unroll
    for (int d = 0; d < 8; ++d) chunkA(d, d);
    chunkB(0, 0);
    chunkB(1, 1);

    // steady state: 56 chunks with A reload 8 ahead, B reload 2 ahead
    for (int oo = 0; oo < 7; ++oo) {
        const int c0 = oo * 8;
#pragma unroll
        for (int ii = 0; ii < 8; ++ii) {
            compute(ii, ii & 1);
            chunkA(c0 + ii + 8, ii);
            chunkB(c0 + ii + 2, ii & 1);
        }
    }
    // tail: chunks 56..63
#pragma unroll
    for (int ii = 0; ii < 8; ++ii) {
        compute(ii, ii & 1);
        if (ii < 6) chunkB(58 + ii, ii & 1);
    }

    float inv[4];
#pragma unroll
    for (int g = 0; g < 4; ++g) inv[g] = 1.0f / dacc[g];

    float* ob = out + (size_t)b * N * F;
#pragma unroll
    for (int ct = 0; ct < 4; ++ct) {
        const int o = wn * 64 + ct * 16 + l15;
#pragma unroll
        for (int g = 0; g < 4; ++g) {
            const int i = i0 + wm * 16 + quad * 4 + g;
            __builtin_nontemporal_store(acc[ct][g] * inv[g], &ob[(size_t)i * F + o]);
        }
    }
}

// ---------------------------------------------------------------------------
extern "C" void kernel_launch(void* const* d_in, const int* in_sizes, int n_in,
                              void* d_out, int out_size, void* d_ws, size_t ws_size,
                              hipStream_t stream) {
    const float* h   = (const float*)d_in[0];
    const float* adj = (const float*)d_in[1];
    const float* W   = (const float*)d_in[2];
    const float* a   = (const float*)d_in[3];
    float* out = (float*)d_out;

    unsigned short* Wb  = (unsigned short*)d_ws;                          // 4 MB
    unsigned short* Wb2 = (unsigned short*)((char*)d_ws + (4u << 20));    // 4 MB
    unsigned short* p16 = (unsigned short*)((char*)d_ws + (8u << 20));    // 32 KB

    k1_wh<<<NB * N / 64, 256, 0, stream>>>(h, W, Wb);
    k2_scale<<<NB * N / (8 * 4), 256, 0, stream>>>(Wb, a, Wb2, p16);
    k3_attn<<<NB * (N / 32), 256, 0, stream>>>(adj, Wb2, p16, out);
}